// Round 1
// baseline (50460.989 us; speedup 1.0000x reference)
//
#include <hip/hip_runtime.h>
#include <hip/hip_bf16.h>
#include <math.h>

// ---------------------------------------------------------------------------
// Direct 3x3 'SAME' conv, NHWC, fp32, with bias. One block = one (n, 8x8-ish
// spatial tile). Activations staged in LDS; weights streamed from global
// (coalesced over the 64 co-lanes, reused across 16 register-blocked
// positions per thread).
// ---------------------------------------------------------------------------
template<int H, int W, int Cin, int Cout, int TH, int TW>
__global__ __launch_bounds__(256) void conv3x3_bias(
    const float* __restrict__ in, const float* __restrict__ wt,
    const float* __restrict__ bias, float* __restrict__ out, int NB)
{
  constexpr int TILES_X = W / TW, TILES_Y = H / TH;
  constexpr int PAD_W = TW + 2, PAD_H = TH + 2;
  constexpr int LDS_N = PAD_H * PAD_W * Cin;
  __shared__ __align__(16) float tile[LDS_N];

  int blk = blockIdx.x;
  int n = blk / (TILES_X * TILES_Y);
  int trem = blk % (TILES_X * TILES_Y);
  int ty = trem / TILES_X, tx = trem % TILES_X;
  int y0 = ty * TH, x0 = tx * TW;
  const float* inN = in + (size_t)n * H * W * Cin;

  for (int i = threadIdx.x; i < LDS_N; i += 256) {
    int ci = i % Cin; int rem = i / Cin;
    int xx = rem % PAD_W; int yy = rem / PAD_W;
    int gy = y0 + yy - 1, gx = x0 + xx - 1;
    float v = 0.f;
    if (gy >= 0 && gy < H && gx >= 0 && gx < W)
      v = inN[((size_t)gy * W + gx) * Cin + ci];
    tile[i] = v;
  }
  __syncthreads();

  constexpr int P = TH * TW;   // positions per block
  constexpr int PPT = P / 4;   // positions per thread (4 waves)
  int lane_co = threadIdx.x & 63;
  int wv = threadIdx.x >> 6;
  float* outN = out + (size_t)n * H * W * Cout;

  for (int cc = 0; cc < Cout; cc += 64) {
    int co = cc + lane_co;
    float acc[PPT];
    float bco = bias[co];
#pragma unroll
    for (int j = 0; j < PPT; ++j) acc[j] = bco;

#pragma unroll
    for (int kh = 0; kh < 3; ++kh)
#pragma unroll
    for (int kw = 0; kw < 3; ++kw) {
      const float* wtap = wt + ((size_t)(kh * 3 + kw) * Cin) * Cout + co;
      if constexpr (Cin % 4 == 0) {
        for (int c4 = 0; c4 < Cin; c4 += 4) {
          float w0 = wtap[(size_t)(c4 + 0) * Cout];
          float w1 = wtap[(size_t)(c4 + 1) * Cout];
          float w2 = wtap[(size_t)(c4 + 2) * Cout];
          float w3 = wtap[(size_t)(c4 + 3) * Cout];
#pragma unroll
          for (int j = 0; j < PPT; ++j) {
            int p = wv * PPT + j;
            int ly = p / TW, lx = p % TW;
            const float4 h4 = *(const float4*)&tile[((ly + kh) * PAD_W + (lx + kw)) * Cin + c4];
            acc[j] += h4.x * w0 + h4.y * w1 + h4.z * w2 + h4.w * w3;
          }
        }
      } else {
        for (int c1 = 0; c1 < Cin; ++c1) {
          float w0 = wtap[(size_t)c1 * Cout];
#pragma unroll
          for (int j = 0; j < PPT; ++j) {
            int p = wv * PPT + j;
            int ly = p / TW, lx = p % TW;
            acc[j] += tile[((ly + kh) * PAD_W + (lx + kw)) * Cin + c1] * w0;
          }
        }
      }
    }
#pragma unroll
    for (int j = 0; j < PPT; ++j) {
      int p = wv * PPT + j;
      int ly = p / TW, lx = p % TW;
      outN[((size_t)(y0 + ly) * W + (x0 + lx)) * Cout + co] = acc[j];
    }
  }
}

// ---------------------------------------------------------------------------
// One ConvLSTM timestep: z = gx[t] + conv3x3(h_prev, Wh); gates i,f,c,o;
// c = hs(zf)*c + hs(zi)*tanh(zc); h = hs(zo)*tanh(c).
// Thread owns one f across all 4 gates for NP register-blocked positions.
// ---------------------------------------------------------------------------
__device__ __forceinline__ float hsig(float x) {
  return fminf(fmaxf(0.2f * x + 0.5f, 0.f), 1.f);
}

template<int H, int W, int F, int TH, int TW>
__global__ __launch_bounds__(256) void lstm_step(
    const float* __restrict__ gx, long gx_bstride,     // pre-offset to slice t
    const float* __restrict__ hprev, long hp_bstride,  // null when first
    const float* __restrict__ wh,                      // (3,3,F,4F)
    float* __restrict__ c,                             // (B,H,W,F)
    float* __restrict__ hout, long ho_bstride,
    int first)
{
  constexpr int TILES_X = W / TW, TILES_Y = H / TH;
  constexpr int PAD_W = TW + 2, PAD_H = TH + 2;
  constexpr int LDS_N = PAD_H * PAD_W * F;
  __shared__ __align__(16) float tile[LDS_N];

  int blk = blockIdx.x;
  int b = blk / (TILES_X * TILES_Y);
  int trem = blk % (TILES_X * TILES_Y);
  int ty = trem / TILES_X, tx = trem % TILES_X;
  int y0 = ty * TH, x0 = tx * TW;

  if (first) {
    for (int i = threadIdx.x; i < LDS_N; i += 256) tile[i] = 0.f;
  } else {
    const float* hb = hprev + (size_t)b * hp_bstride;
    for (int i = threadIdx.x; i < LDS_N; i += 256) {
      int ci = i % F; int rem = i / F;
      int xx = rem % PAD_W, yy = rem / PAD_W;
      int gy = y0 + yy - 1, gxp = x0 + xx - 1;
      float v = 0.f;
      if (gy >= 0 && gy < H && gxp >= 0 && gxp < W)
        v = hb[((size_t)gy * W + gxp) * F + ci];
      tile[i] = v;
    }
  }
  __syncthreads();

  constexpr int G = 256 / F;     // position-groups
  constexpr int P = TH * TW;
  constexpr int NP = P / G;      // positions per thread
  int f = threadIdx.x % F;
  int pg = threadIdx.x / F;

  float acc[4][NP];
  const float* gxb = gx + (size_t)b * gx_bstride;
#pragma unroll
  for (int j = 0; j < NP; ++j) {
    int p = pg * NP + j;
    int gy = y0 + p / TW, gxp = x0 + p % TW;
    size_t base = ((size_t)gy * W + gxp) * 4 * F;
#pragma unroll
    for (int g = 0; g < 4; ++g) acc[g][j] = gxb[base + g * F + f];
  }

#pragma unroll
  for (int kh = 0; kh < 3; ++kh)
#pragma unroll
  for (int kw = 0; kw < 3; ++kw) {
    const float* wtap = wh + ((size_t)(kh * 3 + kw) * F) * 4 * F + f;
    for (int c4 = 0; c4 < F; c4 += 4) {
      float w[4][4];
#pragma unroll
      for (int jj = 0; jj < 4; ++jj)
#pragma unroll
        for (int g = 0; g < 4; ++g)
          w[g][jj] = wtap[(size_t)(c4 + jj) * 4 * F + g * F];
#pragma unroll
      for (int j = 0; j < NP; ++j) {
        int p = pg * NP + j;
        int ly = p / TW, lx = p % TW;
        float4 h4 = *(const float4*)&tile[((ly + kh) * PAD_W + (lx + kw)) * F + c4];
#pragma unroll
        for (int g = 0; g < 4; ++g)
          acc[g][j] += h4.x * w[g][0] + h4.y * w[g][1] + h4.z * w[g][2] + h4.w * w[g][3];
      }
    }
  }

  float* cb = c + (size_t)b * H * W * F;
  float* hb2 = hout + (size_t)b * ho_bstride;
#pragma unroll
  for (int j = 0; j < NP; ++j) {
    int p = pg * NP + j;
    int gy = y0 + p / TW, gxp = x0 + p % TW;
    size_t idx = ((size_t)gy * W + gxp) * F + f;
    float zi = acc[0][j], zf = acc[1][j], zc = acc[2][j], zo = acc[3][j];
    float cold = first ? 0.f : cb[idx];
    float cn = hsig(zf) * cold + hsig(zi) * tanhf(zc);
    cb[idx] = cn;
    hb2[idx] = hsig(zo) * tanhf(cn);
  }
}

// ---------------------------------------------------------------------------
// BatchNorm (affine, eps=1e-3) applied per element, then 2x2 spatial max.
// in: (NT,H,W,F) -> out: (NT,H/2,W/2,F)
// ---------------------------------------------------------------------------
__global__ void bnpool_kernel(const float* __restrict__ in,
                              const float* __restrict__ g, const float* __restrict__ be,
                              const float* __restrict__ m, const float* __restrict__ v,
                              float* __restrict__ out, int total, int H, int W, int F)
{
  int i = blockIdx.x * 256 + threadIdx.x;
  if (i >= total) return;
  int f = i % F; int rem = i / F;
  int x = rem % (W / 2); rem /= (W / 2);
  int y = rem % (H / 2); int nt = rem / (H / 2);
  float scale = g[f] * rsqrtf(v[f] + 1e-3f);
  float shift = be[f] - m[f] * scale;
  const float* base = in + (((size_t)nt * H + 2 * y) * W + 2 * x) * F + f;
  float a0 = base[0] * scale + shift;
  float a1 = base[F] * scale + shift;
  float a2 = base[(size_t)W * F] * scale + shift;
  float a3 = base[(size_t)W * F + F] * scale + shift;
  out[i] = fmaxf(fmaxf(a0, a1), fmaxf(a2, a3));
}

// (8,16,16,64) -> (8,8,8,64) flattened to (8,4096)
__global__ void poolhw_kernel(const float* __restrict__ in, float* __restrict__ out, int total)
{
  int i = blockIdx.x * 256 + threadIdx.x;
  if (i >= total) return;
  int f = i % 64; int rem = i / 64;
  int x = rem % 8; rem /= 8;
  int y = rem % 8; int b = rem / 8;
  const float* base = in + (((size_t)b * 16 + 2 * y) * 16 + 2 * x) * 64 + f;
  float a0 = base[0], a1 = base[64], a2 = base[16 * 64], a3 = base[16 * 64 + 64];
  out[i] = fmaxf(fmaxf(a0, a1), fmaxf(a2, a3));
}

// ---------------------------------------------------------------------------
// Dense (8,K) @ (K,N) + bias, k-split across blockIdx.y, fp32 atomic combine.
// out must be zeroed beforehand; kb==0 adds bias.
// ---------------------------------------------------------------------------
__global__ void dense_part(const float* __restrict__ x, const float* __restrict__ w,
                           const float* __restrict__ bias, float* __restrict__ out,
                           int K, int N, int kchunk)
{
  extern __shared__ float xs[];  // 8 * kchunk
  int co = blockIdx.x * 256 + threadIdx.x;
  int kb = blockIdx.y;
  int k0 = kb * kchunk;
  int k1 = min(k0 + kchunk, K);
  int klen = k1 - k0;
  for (int i = threadIdx.x; i < klen * 8; i += 256) {
    int b = i / klen; int kk = i % klen;
    xs[b * kchunk + kk] = x[(size_t)b * K + k0 + kk];
  }
  __syncthreads();
  if (co >= N) return;
  float acc[8];
#pragma unroll
  for (int b = 0; b < 8; ++b) acc[b] = 0.f;
  for (int k = k0; k < k1; ++k) {
    float wv = w[(size_t)k * N + co];
    int kk = k - k0;
#pragma unroll
    for (int b = 0; b < 8; ++b) acc[b] += xs[b * kchunk + kk] * wv;
  }
  float bi = (kb == 0) ? bias[co] : 0.f;
#pragma unroll
  for (int b = 0; b < 8; ++b) atomicAdd(&out[(size_t)b * N + co], acc[b] + bi);
}

// Final (8,100)@(100,10)+b4 then @(10,1)+bc -> (8,1)
__global__ void dense_tail(const float* __restrict__ d3,
                           const float* __restrict__ w4, const float* __restrict__ b4,
                           const float* __restrict__ wc, const float* __restrict__ bc,
                           float* __restrict__ out)
{
  __shared__ float d4[8][10];
  int t = threadIdx.x;
  if (t < 80) {
    int b = t / 10, co = t % 10;
    float acc = b4[co];
    for (int k = 0; k < 100; ++k) acc += d3[b * 100 + k] * w4[k * 10 + co];
    d4[b][co] = acc;
  }
  __syncthreads();
  if (t < 8) {
    float acc = bc[0];
    for (int j = 0; j < 10; ++j) acc += d4[t][j] * wc[j];
    out[t] = acc;
  }
}

// ---------------------------------------------------------------------------
extern "C" void kernel_launch(void* const* d_in, const int* in_sizes, int n_in,
                              void* d_out, int out_size, void* d_ws, size_t ws_size,
                              hipStream_t stream)
{
  const float* x   = (const float*)d_in[0];
  const float* W1x = (const float*)d_in[1];
  const float* W1h = (const float*)d_in[2];
  const float* b1  = (const float*)d_in[3];
  const float* g1  = (const float*)d_in[4];
  const float* be1 = (const float*)d_in[5];
  const float* m1  = (const float*)d_in[6];
  const float* v1  = (const float*)d_in[7];
  const float* W2x = (const float*)d_in[8];
  const float* W2h = (const float*)d_in[9];
  const float* b2  = (const float*)d_in[10];
  const float* g2  = (const float*)d_in[11];
  const float* be2 = (const float*)d_in[12];
  const float* m2  = (const float*)d_in[13];
  const float* v2  = (const float*)d_in[14];
  const float* W3x = (const float*)d_in[15];
  const float* W3h = (const float*)d_in[16];
  const float* b3  = (const float*)d_in[17];
  const float* Wd1 = (const float*)d_in[18];
  const float* bd1 = (const float*)d_in[19];
  const float* Wd2 = (const float*)d_in[20];
  const float* bd2 = (const float*)d_in[21];
  const float* Wd3 = (const float*)d_in[22];
  const float* bd3 = (const float*)d_in[23];
  const float* Wd4 = (const float*)d_in[24];
  const float* bd4 = (const float*)d_in[25];
  const float* Wc  = (const float*)d_in[26];
  const float* bc  = (const float*)d_in[27];

  // workspace layout (bytes, 256-aligned), with lifetime-based reuse
  char* ws = (char*)d_ws;
  size_t off = 0;
  auto alloc = [&](size_t bytes) { size_t r = off; off = (off + bytes + 255) & ~(size_t)255; return r; };
  size_t oR0   = alloc(100663296);  // gx1(100.7MB) -> gx2(50.3MB) -> gx3(25.2MB)
  size_t oR1   = alloc(25165824);   // hseq1(25.2MB) -> hseq2(12.6MB)
  size_t oR2   = alloc(6291456);    // pool1(6.3MB) -> pool2(3.1MB)
  size_t oR3   = alloc(2097152);    // c1 -> c2 -> c3
  size_t oh3a  = alloc(524288);
  size_t oh3b  = alloc(524288);
  size_t oflat = alloc(131072);
  size_t od1   = alloc(320000);
  size_t od2   = alloc(32000);
  size_t od3   = alloc(3200);
  (void)ws_size; (void)in_sizes; (void)n_in; (void)out_size;

  float* gx1   = (float*)(ws + oR0);
  float* gx2   = (float*)(ws + oR0);
  float* gx3   = (float*)(ws + oR0);
  float* hseq1 = (float*)(ws + oR1);
  float* hseq2 = (float*)(ws + oR1);
  float* pool1 = (float*)(ws + oR2);
  float* pool2 = (float*)(ws + oR2);
  float* cbuf  = (float*)(ws + oR3);
  float* h3a   = (float*)(ws + oh3a);
  float* h3b   = (float*)(ws + oh3b);
  float* flat  = (float*)(ws + oflat);
  float* d1    = (float*)(ws + od1);
  float* d2    = (float*)(ws + od2);
  float* d3b   = (float*)(ws + od3);

  const int B = 8, T = 12;

  // ---- Layer 1: 64x64, Cin=3, F=16 ----
  conv3x3_bias<64, 64, 3, 64, 8, 8><<<96 * 64, 256, 0, stream>>>(x, W1x, b1, gx1, 96);
  {
    const long gxs = (long)T * 64 * 64 * 64;   // batch stride of gx1
    const long hs  = (long)T * 64 * 64 * 16;   // batch stride of hseq1
    for (int t = 0; t < T; ++t) {
      lstm_step<64, 64, 16, 8, 8><<<B * 64, 256, 0, stream>>>(
          gx1 + (size_t)t * 64 * 64 * 64, gxs,
          t ? hseq1 + (size_t)(t - 1) * 64 * 64 * 16 : nullptr, hs,
          W1h, cbuf, hseq1 + (size_t)t * 64 * 64 * 16, hs, t == 0);
    }
  }
  {
    int total = B * T * 32 * 32 * 16;
    bnpool_kernel<<<(total + 255) / 256, 256, 0, stream>>>(hseq1, g1, be1, m1, v1, pool1, total, 64, 64, 16);
  }

  // ---- Layer 2: 32x32, Cin=16, F=32 ----
  conv3x3_bias<32, 32, 16, 128, 8, 8><<<96 * 16, 256, 0, stream>>>(pool1, W2x, b2, gx2, 96);
  {
    const long gxs = (long)T * 32 * 32 * 128;
    const long hs  = (long)T * 32 * 32 * 32;
    for (int t = 0; t < T; ++t) {
      lstm_step<32, 32, 32, 4, 8><<<B * 32, 256, 0, stream>>>(
          gx2 + (size_t)t * 32 * 32 * 128, gxs,
          t ? hseq2 + (size_t)(t - 1) * 32 * 32 * 32 : nullptr, hs,
          W2h, cbuf, hseq2 + (size_t)t * 32 * 32 * 32, hs, t == 0);
    }
  }
  {
    int total = B * T * 16 * 16 * 32;
    bnpool_kernel<<<(total + 255) / 256, 256, 0, stream>>>(hseq2, g2, be2, m2, v2, pool2, total, 32, 32, 32);
  }

  // ---- Layer 3: 16x16, Cin=32, F=64, return last h ----
  conv3x3_bias<16, 16, 32, 256, 8, 8><<<96 * 4, 256, 0, stream>>>(pool2, W3x, b3, gx3, 96);
  {
    const long gxs = (long)T * 16 * 16 * 256;
    const long hs  = (long)16 * 16 * 64;   // ping-pong buffers, batch stride = H*W*F
    for (int t = 0; t < T; ++t) {
      float* hout = (t % 2 == 0) ? h3a : h3b;
      const float* hp = (t % 2 == 0) ? h3b : h3a;
      lstm_step<16, 16, 64, 2, 4><<<B * 32, 256, 0, stream>>>(
          gx3 + (size_t)t * 16 * 16 * 256, gxs,
          t ? hp : nullptr, hs,
          W3h, cbuf, hout, hs, t == 0);
    }
  }
  // final h is h3b (t=11 odd)
  poolhw_kernel<<<(32768 + 255) / 256, 256, 0, stream>>>(h3b, flat, 32768);

  // ---- Dense chain ----
  hipMemsetAsync(d1, 0, 320000, stream);
  hipMemsetAsync(d2, 0, 32000, stream);
  hipMemsetAsync(d3b, 0, 3200, stream);
  dense_part<<<dim3(40, 8), 256, 8 * 512 * 4, stream>>>(flat, Wd1, bd1, d1, 4096, 10000, 512);
  dense_part<<<dim3(4, 20), 256, 8 * 512 * 4, stream>>>(d1, Wd2, bd2, d2, 10000, 1000, 512);
  dense_part<<<dim3(1, 8), 256, 8 * 128 * 4, stream>>>(d2, Wd3, bd3, d3b, 1000, 100, 128);
  dense_tail<<<1, 128, 0, stream>>>(d3b, Wd4, bd4, Wc, bc, (float*)d_out);
}

// Round 2
// 2055.282 us; speedup vs baseline: 24.5519x; 24.5519x over previous
//
#include <hip/hip_runtime.h>
#include <hip/hip_bf16.h>
#include <math.h>

// ---------------------------------------------------------------------------
// Direct 3x3 'SAME' conv, NHWC, fp32, with bias. One block = one (n, spatial
// tile). Activations staged in LDS; weights streamed from global (coalesced
// over the 64 co-lanes, reused across register-blocked positions).
// NOTE: `#pragma unroll 1` on the channel loop is load-bearing — full unroll
// (9 taps x Cin/4) blew VGPRs to 256 and spilled ~1.5 GB/dispatch in R0.
// ---------------------------------------------------------------------------
template<int H, int W, int Cin, int Cout, int TH, int TW>
__global__ __launch_bounds__(256) void conv3x3_bias(
    const float* __restrict__ in, const float* __restrict__ wt,
    const float* __restrict__ bias, float* __restrict__ out, int NB)
{
  constexpr int TILES_X = W / TW, TILES_Y = H / TH;
  constexpr int PAD_W = TW + 2, PAD_H = TH + 2;
  constexpr int LDS_N = PAD_H * PAD_W * Cin;
  __shared__ __align__(16) float tile[LDS_N];

  int blk = blockIdx.x;
  int n = blk / (TILES_X * TILES_Y);
  int trem = blk % (TILES_X * TILES_Y);
  int ty = trem / TILES_X, tx = trem % TILES_X;
  int y0 = ty * TH, x0 = tx * TW;
  const float* inN = in + (size_t)n * H * W * Cin;

  for (int i = threadIdx.x; i < LDS_N; i += 256) {
    int ci = i % Cin; int rem = i / Cin;
    int xx = rem % PAD_W; int yy = rem / PAD_W;
    int gy = y0 + yy - 1, gx = x0 + xx - 1;
    float v = 0.f;
    if (gy >= 0 && gy < H && gx >= 0 && gx < W)
      v = inN[((size_t)gy * W + gx) * Cin + ci];
    tile[i] = v;
  }
  __syncthreads();

  constexpr int P = TH * TW;   // positions per block
  constexpr int PPT = P / 4;   // positions per thread (4 waves)
  int lane_co = threadIdx.x & 63;
  int wv = threadIdx.x >> 6;
  float* outN = out + (size_t)n * H * W * Cout;

  for (int cc = 0; cc < Cout; cc += 64) {
    int co = cc + lane_co;
    float acc[PPT];
    float bco = bias[co];
#pragma unroll
    for (int j = 0; j < PPT; ++j) acc[j] = bco;

#pragma unroll
    for (int kh = 0; kh < 3; ++kh)
#pragma unroll
    for (int kw = 0; kw < 3; ++kw) {
      const float* wtap = wt + ((size_t)(kh * 3 + kw) * Cin) * Cout + co;
      if constexpr (Cin % 4 == 0) {
#pragma unroll 1
        for (int c4 = 0; c4 < Cin; c4 += 4) {
          float w0 = wtap[(size_t)(c4 + 0) * Cout];
          float w1 = wtap[(size_t)(c4 + 1) * Cout];
          float w2 = wtap[(size_t)(c4 + 2) * Cout];
          float w3 = wtap[(size_t)(c4 + 3) * Cout];
#pragma unroll
          for (int j = 0; j < PPT; ++j) {
            int p = wv * PPT + j;
            int ly = p / TW, lx = p % TW;
            const float4 h4 = *(const float4*)&tile[((ly + kh) * PAD_W + (lx + kw)) * Cin + c4];
            acc[j] += h4.x * w0 + h4.y * w1 + h4.z * w2 + h4.w * w3;
          }
        }
      } else {
#pragma unroll 1
        for (int c1 = 0; c1 < Cin; ++c1) {
          float w0 = wtap[(size_t)c1 * Cout];
#pragma unroll
          for (int j = 0; j < PPT; ++j) {
            int p = wv * PPT + j;
            int ly = p / TW, lx = p % TW;
            acc[j] += tile[((ly + kh) * PAD_W + (lx + kw)) * Cin + c1] * w0;
          }
        }
      }
    }
#pragma unroll
    for (int j = 0; j < PPT; ++j) {
      int p = wv * PPT + j;
      int ly = p / TW, lx = p % TW;
      outN[((size_t)(y0 + ly) * W + (x0 + lx)) * Cout + co] = acc[j];
    }
  }
}

// ---------------------------------------------------------------------------
// One ConvLSTM timestep: z = gx[t] + conv3x3(h_prev, Wh); gates i,f,c,o;
// c = hs(zf)*c + hs(zi)*tanh(zc); h = hs(zo)*tanh(c).
// Thread owns one f across all 4 gates for NP register-blocked positions.
// Register budget: acc[4][NP] + h4[NP] + 4 weights, channel loop NOT unrolled.
// ---------------------------------------------------------------------------
__device__ __forceinline__ float hsig(float x) {
  return fminf(fmaxf(0.2f * x + 0.5f, 0.f), 1.f);
}

template<int H, int W, int F, int TH, int TW>
__global__ __launch_bounds__(256) void lstm_step(
    const float* __restrict__ gx, long gx_bstride,     // pre-offset to slice t
    const float* __restrict__ hprev, long hp_bstride,  // null when first
    const float* __restrict__ wh,                      // (3,3,F,4F)
    float* __restrict__ c,                             // (B,H,W,F)
    float* __restrict__ hout, long ho_bstride,
    int first)
{
  constexpr int TILES_X = W / TW, TILES_Y = H / TH;
  constexpr int PAD_W = TW + 2, PAD_H = TH + 2;
  constexpr int LDS_N = PAD_H * PAD_W * F;
  __shared__ __align__(16) float tile[LDS_N];

  int blk = blockIdx.x;
  int b = blk / (TILES_X * TILES_Y);
  int trem = blk % (TILES_X * TILES_Y);
  int ty = trem / TILES_X, tx = trem % TILES_X;
  int y0 = ty * TH, x0 = tx * TW;

  if (first) {
    for (int i = threadIdx.x; i < LDS_N; i += 256) tile[i] = 0.f;
  } else {
    const float* hb = hprev + (size_t)b * hp_bstride;
    for (int i = threadIdx.x; i < LDS_N; i += 256) {
      int ci = i % F; int rem = i / F;
      int xx = rem % PAD_W, yy = rem / PAD_W;
      int gy = y0 + yy - 1, gxp = x0 + xx - 1;
      float v = 0.f;
      if (gy >= 0 && gy < H && gxp >= 0 && gxp < W)
        v = hb[((size_t)gy * W + gxp) * F + ci];
      tile[i] = v;
    }
  }
  __syncthreads();

  constexpr int G = 256 / F;     // position-groups
  constexpr int P = TH * TW;
  constexpr int NP = P / G;      // positions per thread
  int f = threadIdx.x % F;
  int pg = threadIdx.x / F;

  float acc[4][NP];
  const float* gxb = gx + (size_t)b * gx_bstride;
#pragma unroll
  for (int j = 0; j < NP; ++j) {
    int p = pg * NP + j;
    int gy = y0 + p / TW, gxp = x0 + p % TW;
    size_t base = ((size_t)gy * W + gxp) * 4 * F;
#pragma unroll
    for (int g = 0; g < 4; ++g) acc[g][j] = gxb[base + g * F + f];
  }

#pragma unroll
  for (int kh = 0; kh < 3; ++kh)
#pragma unroll
  for (int kw = 0; kw < 3; ++kw) {
    const float* wtap = wh + ((size_t)(kh * 3 + kw) * F) * 4 * F + f;
#pragma unroll 1
    for (int c4 = 0; c4 < F; c4 += 4) {
      float4 h4[NP];
#pragma unroll
      for (int j = 0; j < NP; ++j) {
        int p = pg * NP + j;
        int ly = p / TW, lx = p % TW;
        h4[j] = *(const float4*)&tile[((ly + kh) * PAD_W + (lx + kw)) * F + c4];
      }
      const float* wc0 = wtap + (size_t)c4 * 4 * F;
#pragma unroll
      for (int g = 0; g < 4; ++g) {
        float w0 = wc0[(size_t)g * F];
        float w1 = wc0[(size_t)4 * F + g * F];
        float w2 = wc0[(size_t)8 * F + g * F];
        float w3 = wc0[(size_t)12 * F + g * F];
#pragma unroll
        for (int j = 0; j < NP; ++j)
          acc[g][j] += h4[j].x * w0 + h4[j].y * w1 + h4[j].z * w2 + h4[j].w * w3;
      }
    }
  }

  float* cb = c + (size_t)b * H * W * F;
  float* hb2 = hout + (size_t)b * ho_bstride;
#pragma unroll
  for (int j = 0; j < NP; ++j) {
    int p = pg * NP + j;
    int gy = y0 + p / TW, gxp = x0 + p % TW;
    size_t idx = ((size_t)gy * W + gxp) * F + f;
    float zi = acc[0][j], zf = acc[1][j], zc = acc[2][j], zo = acc[3][j];
    float cold = first ? 0.f : cb[idx];
    float cn = hsig(zf) * cold + hsig(zi) * tanhf(zc);
    cb[idx] = cn;
    hb2[idx] = hsig(zo) * tanhf(cn);
  }
}

// ---------------------------------------------------------------------------
// BatchNorm (affine, eps=1e-3) applied per element, then 2x2 spatial max.
// in: (NT,H,W,F) -> out: (NT,H/2,W/2,F)
// ---------------------------------------------------------------------------
__global__ void bnpool_kernel(const float* __restrict__ in,
                              const float* __restrict__ g, const float* __restrict__ be,
                              const float* __restrict__ m, const float* __restrict__ v,
                              float* __restrict__ out, int total, int H, int W, int F)
{
  int i = blockIdx.x * 256 + threadIdx.x;
  if (i >= total) return;
  int f = i % F; int rem = i / F;
  int x = rem % (W / 2); rem /= (W / 2);
  int y = rem % (H / 2); int nt = rem / (H / 2);
  float scale = g[f] * rsqrtf(v[f] + 1e-3f);
  float shift = be[f] - m[f] * scale;
  const float* base = in + (((size_t)nt * H + 2 * y) * W + 2 * x) * F + f;
  float a0 = base[0] * scale + shift;
  float a1 = base[F] * scale + shift;
  float a2 = base[(size_t)W * F] * scale + shift;
  float a3 = base[(size_t)W * F + F] * scale + shift;
  out[i] = fmaxf(fmaxf(a0, a1), fmaxf(a2, a3));
}

// (8,16,16,64) -> (8,8,8,64) flattened to (8,4096)
__global__ void poolhw_kernel(const float* __restrict__ in, float* __restrict__ out, int total)
{
  int i = blockIdx.x * 256 + threadIdx.x;
  if (i >= total) return;
  int f = i % 64; int rem = i / 64;
  int x = rem % 8; rem /= 8;
  int y = rem % 8; int b = rem / 8;
  const float* base = in + (((size_t)b * 16 + 2 * y) * 16 + 2 * x) * 64 + f;
  float a0 = base[0], a1 = base[64], a2 = base[16 * 64], a3 = base[16 * 64 + 64];
  out[i] = fmaxf(fmaxf(a0, a1), fmaxf(a2, a3));
}

// ---------------------------------------------------------------------------
// Dense (8,K) @ (K,N) + bias, k-split across blockIdx.y, fp32 atomic combine.
// out must be zeroed beforehand; kb==0 adds bias.
// ---------------------------------------------------------------------------
__global__ void dense_part(const float* __restrict__ x, const float* __restrict__ w,
                           const float* __restrict__ bias, float* __restrict__ out,
                           int K, int N, int kchunk)
{
  extern __shared__ float xs[];  // 8 * kchunk
  int co = blockIdx.x * 256 + threadIdx.x;
  int kb = blockIdx.y;
  int k0 = kb * kchunk;
  int k1 = min(k0 + kchunk, K);
  int klen = k1 - k0;
  for (int i = threadIdx.x; i < klen * 8; i += 256) {
    int b = i / klen; int kk = i % klen;
    xs[b * kchunk + kk] = x[(size_t)b * K + k0 + kk];
  }
  __syncthreads();
  if (co >= N) return;
  float acc[8];
#pragma unroll
  for (int b = 0; b < 8; ++b) acc[b] = 0.f;
#pragma unroll 1
  for (int k = k0; k < k1; ++k) {
    float wv = w[(size_t)k * N + co];
    int kk = k - k0;
#pragma unroll
    for (int b = 0; b < 8; ++b) acc[b] += xs[b * kchunk + kk] * wv;
  }
  float bi = (kb == 0) ? bias[co] : 0.f;
#pragma unroll
  for (int b = 0; b < 8; ++b) atomicAdd(&out[(size_t)b * N + co], acc[b] + bi);
}

// Final (8,100)@(100,10)+b4 then @(10,1)+bc -> (8,1)
__global__ void dense_tail(const float* __restrict__ d3,
                           const float* __restrict__ w4, const float* __restrict__ b4,
                           const float* __restrict__ wc, const float* __restrict__ bc,
                           float* __restrict__ out)
{
  __shared__ float d4[8][10];
  int t = threadIdx.x;
  if (t < 80) {
    int b = t / 10, co = t % 10;
    float acc = b4[co];
    for (int k = 0; k < 100; ++k) acc += d3[b * 100 + k] * w4[k * 10 + co];
    d4[b][co] = acc;
  }
  __syncthreads();
  if (t < 8) {
    float acc = bc[0];
    for (int j = 0; j < 10; ++j) acc += d4[t][j] * wc[j];
    out[t] = acc;
  }
}

// ---------------------------------------------------------------------------
extern "C" void kernel_launch(void* const* d_in, const int* in_sizes, int n_in,
                              void* d_out, int out_size, void* d_ws, size_t ws_size,
                              hipStream_t stream)
{
  const float* x   = (const float*)d_in[0];
  const float* W1x = (const float*)d_in[1];
  const float* W1h = (const float*)d_in[2];
  const float* b1  = (const float*)d_in[3];
  const float* g1  = (const float*)d_in[4];
  const float* be1 = (const float*)d_in[5];
  const float* m1  = (const float*)d_in[6];
  const float* v1  = (const float*)d_in[7];
  const float* W2x = (const float*)d_in[8];
  const float* W2h = (const float*)d_in[9];
  const float* b2  = (const float*)d_in[10];
  const float* g2  = (const float*)d_in[11];
  const float* be2 = (const float*)d_in[12];
  const float* m2  = (const float*)d_in[13];
  const float* v2  = (const float*)d_in[14];
  const float* W3x = (const float*)d_in[15];
  const float* W3h = (const float*)d_in[16];
  const float* b3  = (const float*)d_in[17];
  const float* Wd1 = (const float*)d_in[18];
  const float* bd1 = (const float*)d_in[19];
  const float* Wd2 = (const float*)d_in[20];
  const float* bd2 = (const float*)d_in[21];
  const float* Wd3 = (const float*)d_in[22];
  const float* bd3 = (const float*)d_in[23];
  const float* Wd4 = (const float*)d_in[24];
  const float* bd4 = (const float*)d_in[25];
  const float* Wc  = (const float*)d_in[26];
  const float* bc  = (const float*)d_in[27];

  // workspace layout (bytes, 256-aligned), with lifetime-based reuse
  char* ws = (char*)d_ws;
  size_t off = 0;
  auto alloc = [&](size_t bytes) { size_t r = off; off = (off + bytes + 255) & ~(size_t)255; return r; };
  size_t oR0   = alloc(100663296);  // gx1(100.7MB) -> gx2(50.3MB) -> gx3(25.2MB)
  size_t oR1   = alloc(25165824);   // hseq1(25.2MB) -> hseq2(12.6MB)
  size_t oR2   = alloc(6291456);    // pool1(6.3MB) -> pool2(3.1MB)
  size_t oR3   = alloc(2097152);    // c1 -> c2 -> c3
  size_t oh3a  = alloc(524288);
  size_t oh3b  = alloc(524288);
  size_t oflat = alloc(131072);
  size_t od1   = alloc(320000);
  size_t od2   = alloc(32000);
  size_t od3   = alloc(3200);
  (void)ws_size; (void)in_sizes; (void)n_in; (void)out_size;

  float* gx1   = (float*)(ws + oR0);
  float* gx2   = (float*)(ws + oR0);
  float* gx3   = (float*)(ws + oR0);
  float* hseq1 = (float*)(ws + oR1);
  float* hseq2 = (float*)(ws + oR1);
  float* pool1 = (float*)(ws + oR2);
  float* pool2 = (float*)(ws + oR2);
  float* cbuf  = (float*)(ws + oR3);
  float* h3a   = (float*)(ws + oh3a);
  float* h3b   = (float*)(ws + oh3b);
  float* flat  = (float*)(ws + oflat);
  float* d1    = (float*)(ws + od1);
  float* d2    = (float*)(ws + od2);
  float* d3b   = (float*)(ws + od3);

  const int B = 8, T = 12;

  // ---- Layer 1: 64x64, Cin=3, F=16 ----
  conv3x3_bias<64, 64, 3, 64, 8, 8><<<96 * 64, 256, 0, stream>>>(x, W1x, b1, gx1, 96);
  {
    const long gxs = (long)T * 64 * 64 * 64;   // batch stride of gx1
    const long hs  = (long)T * 64 * 64 * 16;   // batch stride of hseq1
    for (int t = 0; t < T; ++t) {
      lstm_step<64, 64, 16, 8, 8><<<B * 64, 256, 0, stream>>>(
          gx1 + (size_t)t * 64 * 64 * 64, gxs,
          t ? hseq1 + (size_t)(t - 1) * 64 * 64 * 16 : nullptr, hs,
          W1h, cbuf, hseq1 + (size_t)t * 64 * 64 * 16, hs, t == 0);
    }
  }
  {
    int total = B * T * 32 * 32 * 16;
    bnpool_kernel<<<(total + 255) / 256, 256, 0, stream>>>(hseq1, g1, be1, m1, v1, pool1, total, 64, 64, 16);
  }

  // ---- Layer 2: 32x32, Cin=16, F=32 ----
  conv3x3_bias<32, 32, 16, 128, 8, 8><<<96 * 16, 256, 0, stream>>>(pool1, W2x, b2, gx2, 96);
  {
    const long gxs = (long)T * 32 * 32 * 128;
    const long hs  = (long)T * 32 * 32 * 32;
    for (int t = 0; t < T; ++t) {
      lstm_step<32, 32, 32, 4, 8><<<B * 32, 256, 0, stream>>>(
          gx2 + (size_t)t * 32 * 32 * 128, gxs,
          t ? hseq2 + (size_t)(t - 1) * 32 * 32 * 32 : nullptr, hs,
          W2h, cbuf, hseq2 + (size_t)t * 32 * 32 * 32, hs, t == 0);
    }
  }
  {
    int total = B * T * 16 * 16 * 32;
    bnpool_kernel<<<(total + 255) / 256, 256, 0, stream>>>(hseq2, g2, be2, m2, v2, pool2, total, 32, 32, 32);
  }

  // ---- Layer 3: 16x16, Cin=32, F=64, return last h ----
  conv3x3_bias<16, 16, 32, 256, 8, 8><<<96 * 4, 256, 0, stream>>>(pool2, W3x, b3, gx3, 96);
  {
    const long gxs = (long)T * 16 * 16 * 256;
    const long hs  = (long)16 * 16 * 64;   // ping-pong buffers, batch stride = H*W*F
    for (int t = 0; t < T; ++t) {
      float* hout = (t % 2 == 0) ? h3a : h3b;
      const float* hp = (t % 2 == 0) ? h3b : h3a;
      lstm_step<16, 16, 64, 2, 4><<<B * 32, 256, 0, stream>>>(
          gx3 + (size_t)t * 16 * 16 * 256, gxs,
          t ? hp : nullptr, hs,
          W3h, cbuf, hout, hs, t == 0);
    }
  }
  // final h is h3b (t=11 odd)
  poolhw_kernel<<<(32768 + 255) / 256, 256, 0, stream>>>(h3b, flat, 32768);

  // ---- Dense chain ----
  hipMemsetAsync(d1, 0, 320000, stream);
  hipMemsetAsync(d2, 0, 32000, stream);
  hipMemsetAsync(d3b, 0, 3200, stream);
  dense_part<<<dim3(40, 8), 256, 8 * 512 * 4, stream>>>(flat, Wd1, bd1, d1, 4096, 10000, 512);
  dense_part<<<dim3(4, 20), 256, 8 * 512 * 4, stream>>>(d1, Wd2, bd2, d2, 10000, 1000, 512);
  dense_part<<<dim3(1, 8), 256, 8 * 128 * 4, stream>>>(d2, Wd3, bd3, d3b, 1000, 100, 128);
  dense_tail<<<1, 128, 0, stream>>>(d3b, Wd4, bd4, Wc, bc, (float*)d_out);
}

// Round 3
// 1579.578 us; speedup vs baseline: 31.9459x; 1.3012x over previous
//
#include <hip/hip_runtime.h>
#include <hip/hip_bf16.h>
#include <math.h>

// ---------------------------------------------------------------------------
// Direct 3x3 'SAME' conv, NHWC, fp32, with bias. One block = one (n, spatial
// tile, 64-wide Cout chunk via blockIdx.y). Activations staged in LDS.
// NOTE: `#pragma unroll 1` on the channel loop is load-bearing — full unroll
// blew VGPRs to 256 and spilled ~1.5 GB/dispatch in R0.
// ---------------------------------------------------------------------------
template<int H, int W, int Cin, int Cout, int TH, int TW>
__global__ __launch_bounds__(256) void conv3x3_bias(
    const float* __restrict__ in, const float* __restrict__ wt,
    const float* __restrict__ bias, float* __restrict__ out, int NB)
{
  constexpr int TILES_X = W / TW, TILES_Y = H / TH;
  constexpr int PAD_W = TW + 2, PAD_H = TH + 2;
  constexpr int LDS_N = PAD_H * PAD_W * Cin;
  __shared__ __align__(16) float tile[LDS_N];

  int blk = blockIdx.x;
  int n = blk / (TILES_X * TILES_Y);
  int trem = blk % (TILES_X * TILES_Y);
  int ty = trem / TILES_X, tx = trem % TILES_X;
  int y0 = ty * TH, x0 = tx * TW;
  const float* inN = in + (size_t)n * H * W * Cin;

  for (int i = threadIdx.x; i < LDS_N; i += 256) {
    int ci = i % Cin; int rem = i / Cin;
    int xx = rem % PAD_W; int yy = rem / PAD_W;
    int gy = y0 + yy - 1, gx = x0 + xx - 1;
    float v = 0.f;
    if (gy >= 0 && gy < H && gx >= 0 && gx < W)
      v = inN[((size_t)gy * W + gx) * Cin + ci];
    tile[i] = v;
  }
  __syncthreads();

  constexpr int P = TH * TW;   // positions per block
  constexpr int PPT = P / 4;   // positions per thread (4 waves)
  int lane_co = threadIdx.x & 63;
  int wv = threadIdx.x >> 6;
  float* outN = out + (size_t)n * H * W * Cout;

  int cc = blockIdx.y * 64;    // Cout chunk (occupancy split)
  {
    int co = cc + lane_co;
    float acc[PPT];
    float bco = bias[co];
#pragma unroll
    for (int j = 0; j < PPT; ++j) acc[j] = bco;

#pragma unroll
    for (int kh = 0; kh < 3; ++kh)
#pragma unroll
    for (int kw = 0; kw < 3; ++kw) {
      const float* wtap = wt + ((size_t)(kh * 3 + kw) * Cin) * Cout + co;
      if constexpr (Cin % 4 == 0) {
#pragma unroll 1
        for (int c4 = 0; c4 < Cin; c4 += 4) {
          float w0 = wtap[(size_t)(c4 + 0) * Cout];
          float w1 = wtap[(size_t)(c4 + 1) * Cout];
          float w2 = wtap[(size_t)(c4 + 2) * Cout];
          float w3 = wtap[(size_t)(c4 + 3) * Cout];
#pragma unroll
          for (int j = 0; j < PPT; ++j) {
            int p = wv * PPT + j;
            int ly = p / TW, lx = p % TW;
            const float4 h4 = *(const float4*)&tile[((ly + kh) * PAD_W + (lx + kw)) * Cin + c4];
            acc[j] += h4.x * w0 + h4.y * w1 + h4.z * w2 + h4.w * w3;
          }
        }
      } else {
#pragma unroll 1
        for (int c1 = 0; c1 < Cin; ++c1) {
          float w0 = wtap[(size_t)c1 * Cout];
#pragma unroll
          for (int j = 0; j < PPT; ++j) {
            int p = wv * PPT + j;
            int ly = p / TW, lx = p % TW;
            acc[j] += tile[((ly + kh) * PAD_W + (lx + kw)) * Cin + c1] * w0;
          }
        }
      }
    }
#pragma unroll
    for (int j = 0; j < PPT; ++j) {
      int p = wv * PPT + j;
      int ly = p / TW, lx = p % TW;
      outN[((size_t)(y0 + ly) * W + (x0 + lx)) * Cout + co] = acc[j];
    }
  }
}

// ---------------------------------------------------------------------------
// One ConvLSTM timestep: z = gx[t] + conv3x3(h_prev, Wh); gates i,f,c,o;
// c = hs(zf)*c + hs(zi)*tanh(zc); h = hs(zo)*tanh(c).
// Register budget: acc[4][NP] + h4[NP] + 4 weights, channel loop NOT unrolled.
// ---------------------------------------------------------------------------
__device__ __forceinline__ float hsig(float x) {
  return fminf(fmaxf(0.2f * x + 0.5f, 0.f), 1.f);
}

template<int H, int W, int F, int TH, int TW>
__global__ __launch_bounds__(256) void lstm_step(
    const float* __restrict__ gx, long gx_bstride,     // pre-offset to slice t
    const float* __restrict__ hprev, long hp_bstride,  // null when first
    const float* __restrict__ wh,                      // (3,3,F,4F)
    float* __restrict__ c,                             // (B,H,W,F)
    float* __restrict__ hout, long ho_bstride,
    int first)
{
  constexpr int TILES_X = W / TW, TILES_Y = H / TH;
  constexpr int PAD_W = TW + 2, PAD_H = TH + 2;
  constexpr int LDS_N = PAD_H * PAD_W * F;
  __shared__ __align__(16) float tile[LDS_N];

  int blk = blockIdx.x;
  int b = blk / (TILES_X * TILES_Y);
  int trem = blk % (TILES_X * TILES_Y);
  int ty = trem / TILES_X, tx = trem % TILES_X;
  int y0 = ty * TH, x0 = tx * TW;

  if (first) {
    for (int i = threadIdx.x; i < LDS_N; i += 256) tile[i] = 0.f;
  } else {
    const float* hb = hprev + (size_t)b * hp_bstride;
    for (int i = threadIdx.x; i < LDS_N; i += 256) {
      int ci = i % F; int rem = i / F;
      int xx = rem % PAD_W, yy = rem / PAD_W;
      int gy = y0 + yy - 1, gxp = x0 + xx - 1;
      float v = 0.f;
      if (gy >= 0 && gy < H && gxp >= 0 && gxp < W)
        v = hb[((size_t)gy * W + gxp) * F + ci];
      tile[i] = v;
    }
  }
  __syncthreads();

  constexpr int G = 256 / F;     // position-groups
  constexpr int P = TH * TW;
  constexpr int NP = P / G;      // positions per thread
  int f = threadIdx.x % F;
  int pg = threadIdx.x / F;

  float acc[4][NP];
  const float* gxb = gx + (size_t)b * gx_bstride;
#pragma unroll
  for (int j = 0; j < NP; ++j) {
    int p = pg * NP + j;
    int gy = y0 + p / TW, gxp = x0 + p % TW;
    size_t base = ((size_t)gy * W + gxp) * 4 * F;
#pragma unroll
    for (int g = 0; g < 4; ++g) acc[g][j] = gxb[base + g * F + f];
  }

#pragma unroll
  for (int kh = 0; kh < 3; ++kh)
#pragma unroll
  for (int kw = 0; kw < 3; ++kw) {
    const float* wtap = wh + ((size_t)(kh * 3 + kw) * F) * 4 * F + f;
#pragma unroll 1
    for (int c4 = 0; c4 < F; c4 += 4) {
      float4 h4[NP];
#pragma unroll
      for (int j = 0; j < NP; ++j) {
        int p = pg * NP + j;
        int ly = p / TW, lx = p % TW;
        h4[j] = *(const float4*)&tile[((ly + kh) * PAD_W + (lx + kw)) * F + c4];
      }
      const float* wc0 = wtap + (size_t)c4 * 4 * F;
#pragma unroll
      for (int g = 0; g < 4; ++g) {
        float w0 = wc0[(size_t)g * F];
        float w1 = wc0[(size_t)4 * F + g * F];
        float w2 = wc0[(size_t)8 * F + g * F];
        float w3 = wc0[(size_t)12 * F + g * F];
#pragma unroll
        for (int j = 0; j < NP; ++j)
          acc[g][j] += h4[j].x * w0 + h4[j].y * w1 + h4[j].z * w2 + h4[j].w * w3;
      }
    }
  }

  float* cb = c + (size_t)b * H * W * F;
  float* hb2 = hout + (size_t)b * ho_bstride;
#pragma unroll
  for (int j = 0; j < NP; ++j) {
    int p = pg * NP + j;
    int gy = y0 + p / TW, gxp = x0 + p % TW;
    size_t idx = ((size_t)gy * W + gxp) * F + f;
    float zi = acc[0][j], zf = acc[1][j], zc = acc[2][j], zo = acc[3][j];
    float cold = first ? 0.f : cb[idx];
    float cn = hsig(zf) * cold + hsig(zi) * tanhf(zc);
    cb[idx] = cn;
    hb2[idx] = hsig(zo) * tanhf(cn);
  }
}

// ---------------------------------------------------------------------------
// BatchNorm (affine, eps=1e-3) applied per element, then 2x2 spatial max.
// ---------------------------------------------------------------------------
__global__ void bnpool_kernel(const float* __restrict__ in,
                              const float* __restrict__ g, const float* __restrict__ be,
                              const float* __restrict__ m, const float* __restrict__ v,
                              float* __restrict__ out, int total, int H, int W, int F)
{
  int i = blockIdx.x * 256 + threadIdx.x;
  if (i >= total) return;
  int f = i % F; int rem = i / F;
  int x = rem % (W / 2); rem /= (W / 2);
  int y = rem % (H / 2); int nt = rem / (H / 2);
  float scale = g[f] * rsqrtf(v[f] + 1e-3f);
  float shift = be[f] - m[f] * scale;
  const float* base = in + (((size_t)nt * H + 2 * y) * W + 2 * x) * F + f;
  float a0 = base[0] * scale + shift;
  float a1 = base[F] * scale + shift;
  float a2 = base[(size_t)W * F] * scale + shift;
  float a3 = base[(size_t)W * F + F] * scale + shift;
  out[i] = fmaxf(fmaxf(a0, a1), fmaxf(a2, a3));
}

// (8,16,16,64) -> (8,8,8,64) flattened to (8,4096)
__global__ void poolhw_kernel(const float* __restrict__ in, float* __restrict__ out, int total)
{
  int i = blockIdx.x * 256 + threadIdx.x;
  if (i >= total) return;
  int f = i % 64; int rem = i / 64;
  int x = rem % 8; rem /= 8;
  int y = rem % 8; int b = rem / 8;
  const float* base = in + (((size_t)b * 16 + 2 * y) * 16 + 2 * x) * 64 + f;
  float a0 = base[0], a1 = base[64], a2 = base[16 * 64], a3 = base[16 * 64 + 64];
  out[i] = fmaxf(fmaxf(a0, a1), fmaxf(a2, a3));
}

// ---------------------------------------------------------------------------
// Dense (8,K)@(K,N): stage 1 writes k-split partials (no atomics), stage 2
// reduces + bias. x rows staged in LDS as [kk][b] so per-k the 8 batch values
// are two broadcast ds_read_b128.
// ---------------------------------------------------------------------------
__global__ __launch_bounds__(256) void dense_partial(
    const float* __restrict__ x, const float* __restrict__ w,
    float* __restrict__ part, int K, int N, int kchunk)
{
  extern __shared__ __align__(16) float xs[];  // kchunk*8, layout [kk][b]
  int kb = blockIdx.y;
  int k0 = kb * kchunk;
  int klen = min(kchunk, K - k0);
  for (int i = threadIdx.x; i < klen * 8; i += 256) {
    int kk = i >> 3, b = i & 7;
    xs[i] = x[(size_t)b * K + k0 + kk];
  }
  __syncthreads();
  int co = blockIdx.x * 256 + threadIdx.x;
  if (co >= N) return;
  float acc[8];
#pragma unroll
  for (int b = 0; b < 8; ++b) acc[b] = 0.f;
  const float4* xs4 = (const float4*)xs;
  const float* wp = w + (size_t)k0 * N + co;
#pragma unroll 4
  for (int kk = 0; kk < klen; ++kk) {
    float wv = wp[(size_t)kk * N];
    float4 lo = xs4[kk * 2], hi = xs4[kk * 2 + 1];
    acc[0] += lo.x * wv; acc[1] += lo.y * wv;
    acc[2] += lo.z * wv; acc[3] += lo.w * wv;
    acc[4] += hi.x * wv; acc[5] += hi.y * wv;
    acc[6] += hi.z * wv; acc[7] += hi.w * wv;
  }
#pragma unroll
  for (int b = 0; b < 8; ++b)
    part[((size_t)kb * 8 + b) * N + co] = acc[b];
}

__global__ __launch_bounds__(256) void dense_reduce(
    const float* __restrict__ part, const float* __restrict__ bias,
    float* __restrict__ out, int N, int S)
{
  int co = blockIdx.x * 256 + threadIdx.x;
  int b = blockIdx.y;
  if (co >= N) return;
  float acc = bias[co];
#pragma unroll 4
  for (int kb = 0; kb < S; ++kb)
    acc += part[((size_t)kb * 8 + b) * N + co];
  out[(size_t)b * N + co] = acc;
}

// Small dense with k-split atomics (kept for the tiny 1000->100 layer).
__global__ void dense_part(const float* __restrict__ x, const float* __restrict__ w,
                           const float* __restrict__ bias, float* __restrict__ out,
                           int K, int N, int kchunk)
{
  extern __shared__ float xs[];  // 8 * kchunk
  int co = blockIdx.x * 256 + threadIdx.x;
  int kb = blockIdx.y;
  int k0 = kb * kchunk;
  int k1 = min(k0 + kchunk, K);
  int klen = k1 - k0;
  for (int i = threadIdx.x; i < klen * 8; i += 256) {
    int b = i / klen; int kk = i % klen;
    xs[b * kchunk + kk] = x[(size_t)b * K + k0 + kk];
  }
  __syncthreads();
  if (co >= N) return;
  float acc[8];
#pragma unroll
  for (int b = 0; b < 8; ++b) acc[b] = 0.f;
#pragma unroll 1
  for (int k = k0; k < k1; ++k) {
    float wv = w[(size_t)k * N + co];
    int kk = k - k0;
#pragma unroll
    for (int b = 0; b < 8; ++b) acc[b] += xs[b * kchunk + kk] * wv;
  }
  float bi = (kb == 0) ? bias[co] : 0.f;
#pragma unroll
  for (int b = 0; b < 8; ++b) atomicAdd(&out[(size_t)b * N + co], acc[b] + bi);
}

// Final (8,100)@(100,10)+b4 then @(10,1)+bc -> (8,1)
__global__ void dense_tail(const float* __restrict__ d3,
                           const float* __restrict__ w4, const float* __restrict__ b4,
                           const float* __restrict__ wc, const float* __restrict__ bc,
                           float* __restrict__ out)
{
  __shared__ float d4[8][10];
  int t = threadIdx.x;
  if (t < 80) {
    int b = t / 10, co = t % 10;
    float acc = b4[co];
    for (int k = 0; k < 100; ++k) acc += d3[b * 100 + k] * w4[k * 10 + co];
    d4[b][co] = acc;
  }
  __syncthreads();
  if (t < 8) {
    float acc = bc[0];
    for (int j = 0; j < 10; ++j) acc += d4[t][j] * wc[j];
    out[t] = acc;
  }
}

// ---------------------------------------------------------------------------
extern "C" void kernel_launch(void* const* d_in, const int* in_sizes, int n_in,
                              void* d_out, int out_size, void* d_ws, size_t ws_size,
                              hipStream_t stream)
{
  const float* x   = (const float*)d_in[0];
  const float* W1x = (const float*)d_in[1];
  const float* W1h = (const float*)d_in[2];
  const float* b1  = (const float*)d_in[3];
  const float* g1  = (const float*)d_in[4];
  const float* be1 = (const float*)d_in[5];
  const float* m1  = (const float*)d_in[6];
  const float* v1  = (const float*)d_in[7];
  const float* W2x = (const float*)d_in[8];
  const float* W2h = (const float*)d_in[9];
  const float* b2  = (const float*)d_in[10];
  const float* g2  = (const float*)d_in[11];
  const float* be2 = (const float*)d_in[12];
  const float* m2  = (const float*)d_in[13];
  const float* v2  = (const float*)d_in[14];
  const float* W3x = (const float*)d_in[15];
  const float* W3h = (const float*)d_in[16];
  const float* b3  = (const float*)d_in[17];
  const float* Wd1 = (const float*)d_in[18];
  const float* bd1 = (const float*)d_in[19];
  const float* Wd2 = (const float*)d_in[20];
  const float* bd2 = (const float*)d_in[21];
  const float* Wd3 = (const float*)d_in[22];
  const float* bd3 = (const float*)d_in[23];
  const float* Wd4 = (const float*)d_in[24];
  const float* bd4 = (const float*)d_in[25];
  const float* Wc  = (const float*)d_in[26];
  const float* bc  = (const float*)d_in[27];

  // workspace layout (bytes, 256-aligned), with lifetime-based reuse
  char* ws = (char*)d_ws;
  size_t off = 0;
  auto alloc = [&](size_t bytes) { size_t r = off; off = (off + bytes + 255) & ~(size_t)255; return r; };
  size_t oR0   = alloc(100663296);  // gx1 -> gx2 -> gx3; then part1/part2 for dense
  size_t oR1   = alloc(25165824);   // hseq1 -> hseq2
  size_t oR2   = alloc(6291456);    // pool1 -> pool2
  size_t oR3   = alloc(2097152);    // c buffer
  size_t oh3a  = alloc(524288);
  size_t oh3b  = alloc(524288);
  size_t oflat = alloc(131072);
  size_t od1   = alloc(320000);
  size_t od2   = alloc(32000);
  size_t od3   = alloc(3200);
  (void)ws_size; (void)in_sizes; (void)n_in; (void)out_size;

  float* gx1   = (float*)(ws + oR0);
  float* gx2   = (float*)(ws + oR0);
  float* gx3   = (float*)(ws + oR0);
  float* part1 = (float*)(ws + oR0);             // 64*8*10000*4 = 20.5 MB (gx dead)
  float* part2 = (float*)(ws + oR0 + 33554432);  // 125*8*1000*4 = 4 MB
  float* hseq1 = (float*)(ws + oR1);
  float* hseq2 = (float*)(ws + oR1);
  float* pool1 = (float*)(ws + oR2);
  float* pool2 = (float*)(ws + oR2);
  float* cbuf  = (float*)(ws + oR3);
  float* h3a   = (float*)(ws + oh3a);
  float* h3b   = (float*)(ws + oh3b);
  float* flat  = (float*)(ws + oflat);
  float* d1    = (float*)(ws + od1);
  float* d2    = (float*)(ws + od2);
  float* d3b   = (float*)(ws + od3);

  const int B = 8, T = 12;

  // ---- Layer 1: 64x64, Cin=3, F=16 ----
  conv3x3_bias<64, 64, 3, 64, 8, 8><<<dim3(96 * 64, 1), 256, 0, stream>>>(x, W1x, b1, gx1, 96);
  {
    const long gxs = (long)T * 64 * 64 * 64;
    const long hs  = (long)T * 64 * 64 * 16;
    for (int t = 0; t < T; ++t) {
      lstm_step<64, 64, 16, 8, 8><<<B * 64, 256, 0, stream>>>(
          gx1 + (size_t)t * 64 * 64 * 64, gxs,
          t ? hseq1 + (size_t)(t - 1) * 64 * 64 * 16 : nullptr, hs,
          W1h, cbuf, hseq1 + (size_t)t * 64 * 64 * 16, hs, t == 0);
    }
  }
  {
    int total = B * T * 32 * 32 * 16;
    bnpool_kernel<<<(total + 255) / 256, 256, 0, stream>>>(hseq1, g1, be1, m1, v1, pool1, total, 64, 64, 16);
  }

  // ---- Layer 2: 32x32, Cin=16, F=32 ----
  conv3x3_bias<32, 32, 16, 128, 8, 8><<<dim3(96 * 16, 2), 256, 0, stream>>>(pool1, W2x, b2, gx2, 96);
  {
    const long gxs = (long)T * 32 * 32 * 128;
    const long hs  = (long)T * 32 * 32 * 32;
    for (int t = 0; t < T; ++t) {
      lstm_step<32, 32, 32, 4, 4><<<B * 64, 256, 0, stream>>>(
          gx2 + (size_t)t * 32 * 32 * 128, gxs,
          t ? hseq2 + (size_t)(t - 1) * 32 * 32 * 32 : nullptr, hs,
          W2h, cbuf, hseq2 + (size_t)t * 32 * 32 * 32, hs, t == 0);
    }
  }
  {
    int total = B * T * 16 * 16 * 32;
    bnpool_kernel<<<(total + 255) / 256, 256, 0, stream>>>(hseq2, g2, be2, m2, v2, pool2, total, 32, 32, 32);
  }

  // ---- Layer 3: 16x16, Cin=32, F=64, return last h ----
  conv3x3_bias<16, 16, 32, 256, 8, 8><<<dim3(96 * 4, 4), 256, 0, stream>>>(pool2, W3x, b3, gx3, 96);
  {
    const long gxs = (long)T * 16 * 16 * 256;
    const long hs  = (long)16 * 16 * 64;
    for (int t = 0; t < T; ++t) {
      float* hout = (t % 2 == 0) ? h3a : h3b;
      const float* hp = (t % 2 == 0) ? h3b : h3a;
      lstm_step<16, 16, 64, 2, 4><<<B * 32, 256, 0, stream>>>(
          gx3 + (size_t)t * 16 * 16 * 256, gxs,
          t ? hp : nullptr, hs,
          W3h, cbuf, hout, hs, t == 0);
    }
  }
  // final h is h3b (t=11 odd)
  poolhw_kernel<<<(32768 + 255) / 256, 256, 0, stream>>>(h3b, flat, 32768);

  // ---- Dense chain: partial (k-split, no atomics) + reduce ----
  dense_partial<<<dim3(40, 64), 256, 64 * 8 * 4, stream>>>(flat, Wd1, part1, 4096, 10000, 64);
  dense_reduce<<<dim3(40, 8), 256, 0, stream>>>(part1, bd1, d1, 10000, 64);
  dense_partial<<<dim3(4, 125), 256, 80 * 8 * 4, stream>>>(d1, Wd2, part2, 10000, 1000, 80);
  dense_reduce<<<dim3(4, 8), 256, 0, stream>>>(part2, bd2, d2, 1000, 125);
  hipMemsetAsync(d3b, 0, 3200, stream);
  dense_part<<<dim3(1, 8), 256, 8 * 128 * 4, stream>>>(d2, Wd3, bd3, d3b, 1000, 100, 128);
  dense_tail<<<1, 128, 0, stream>>>(d3b, Wd4, bd4, Wc, bc, (float*)d_out);
}